// Round 1
// baseline (421.264 us; speedup 1.0000x reference)
//
#include <hip/hip_runtime.h>
#include <math.h>

#define VOCAB 100000
#define HID 256
#define BATCH 4096
#define BN_EPS 1e-5f
#define TPB1 512      // tokens per block in k1
#define ROWS2 16      // batch rows per block in k2

// ws layout (in floats)
#define WS_SEGSUM 0
#define WS_COUNTS (BATCH * HID)            // 1048576
#define WS_COLSUM (WS_COUNTS + BATCH)      // +4096
#define WS_COLSQ  (WS_COLSUM + HID)
#define WS_SCALE  (WS_COLSQ + HID)
#define WS_SHIFT  (WS_SCALE + HID)
#define WS_ZERO_FLOATS WS_SCALE            // zero: seg_sum, counts, colsum, colsq

// ---------------------------------------------------------------------------
// k1: ragged embedding gather + segment sum + counts.
// segment_ids sorted -> accumulate runs in registers, flush via atomicAdd at
// run boundaries only (~2-3 flushes per 512-token block).
// Thread h owns hidden column h; loads coalesced (64 lanes x 4B contiguous).
// ---------------------------------------------------------------------------
__global__ __launch_bounds__(256) void k1_gather_segsum(
    const int* __restrict__ token_ids, const int* __restrict__ segment_ids,
    const float* __restrict__ emb, float* __restrict__ seg_sum,
    float* __restrict__ counts, int T)
{
    __shared__ int s_tok[TPB1];
    __shared__ int s_seg[TPB1];
    const int tid = threadIdx.x;
    const int t0  = blockIdx.x * TPB1;
    const int n   = min(TPB1, T - t0);
    if (n <= 0) return;
    for (int i = tid; i < n; i += 256) {
        s_tok[i] = token_ids[t0 + i];
        s_seg[i] = segment_ids[t0 + i];
    }
    __syncthreads();

    const int h = tid;
    float acc  = 0.f;
    int   cur  = s_seg[0];
    int   runlen = 0;
    for (int i = 0; i < n; ++i) {
        int seg = s_seg[i];            // LDS broadcast, uniform across wave
        if (seg != cur) {              // uniform branch
            atomicAdd(&seg_sum[(size_t)cur * HID + h], acc);
            if (h == 0) atomicAdd(&counts[cur], (float)runlen);
            acc = 0.f; runlen = 0; cur = seg;
        }
        acc += emb[(size_t)s_tok[i] * HID + h];
        runlen++;
    }
    atomicAdd(&seg_sum[(size_t)cur * HID + h], acc);
    if (h == 0) atomicAdd(&counts[cur], (float)runlen);
}

// ---------------------------------------------------------------------------
// k2: h = (seg_sum/max(counts,1)) @ W1^T + b1, fused with BN column partials.
// 16-row tile in LDS; thread j computes column j for all 16 rows.
// hout aliases seg_sum (safe: tile fully staged to LDS before writes; each
// row touched by exactly one block). NOTE: no __restrict__ on those two.
// ---------------------------------------------------------------------------
__global__ __launch_bounds__(256) void k2_gemm_bn_partial(
    const float* seg_sum, const float* __restrict__ counts,
    const float* __restrict__ W1, const float* __restrict__ b1,
    float* hout, float* __restrict__ colsum, float* __restrict__ colsq)
{
    __shared__ float s_bow[ROWS2][HID];
    const int tid = threadIdx.x;
    const int b0  = blockIdx.x * ROWS2;

    for (int r = 0; r < ROWS2; ++r) {
        float c   = counts[b0 + r];
        float inv = 1.f / fmaxf(c, 1.f);
        s_bow[r][tid] = seg_sum[(size_t)(b0 + r) * HID + tid] * inv;
    }
    __syncthreads();

    const int j = tid;
    float acc[ROWS2];
    const float bj = b1[j];
#pragma unroll
    for (int r = 0; r < ROWS2; ++r) acc[r] = bj;

    const float4* W1v = reinterpret_cast<const float4*>(W1 + (size_t)j * HID);
    for (int k4 = 0; k4 < HID / 4; ++k4) {
        float4 w = W1v[k4];
#pragma unroll
        for (int r = 0; r < ROWS2; ++r) {
            const float4* bv = reinterpret_cast<const float4*>(&s_bow[r][0]);
            float4 bb = bv[k4];          // ds_read_b128, broadcast (same addr)
            acc[r] = fmaf(bb.x, w.x, acc[r]);
            acc[r] = fmaf(bb.y, w.y, acc[r]);
            acc[r] = fmaf(bb.z, w.z, acc[r]);
            acc[r] = fmaf(bb.w, w.w, acc[r]);
        }
    }

    float ls = 0.f, lq = 0.f;
#pragma unroll
    for (int r = 0; r < ROWS2; ++r) {
        float v = acc[r];
        hout[(size_t)(b0 + r) * HID + j] = v;   // coalesced
        ls += v;
        lq += v * v;
    }
    atomicAdd(&colsum[j], ls);
    atomicAdd(&colsq[j], lq);
}

// ---------------------------------------------------------------------------
// k4: finalize BN scale/shift per column. 1 block, 256 threads.
// ---------------------------------------------------------------------------
__global__ void k4_finalize(
    const float* __restrict__ colsum, const float* __restrict__ colsq,
    const float* __restrict__ gamma, const float* __restrict__ beta,
    float* __restrict__ scale, float* __restrict__ shift)
{
    const int j = threadIdx.x;
    const float mu  = colsum[j] * (1.f / BATCH);
    const float msq = colsq[j]  * (1.f / BATCH);
    const float var = msq - mu * mu;       // biased var
    const float s   = gamma[j] * rsqrtf(var + BN_EPS);
    scale[j] = s;
    shift[j] = beta[j] - mu * s;
}

// ---------------------------------------------------------------------------
// k5: BN apply + ReLU + logits (dot with W2) + BCE loss.
// One 64-lane wave per 16 rows; shuffle reduction; lane 0 writes logit and
// accumulates BCE locally, one atomicAdd into out[0] per wave.
// out[0] = loss, out[1..BATCH] = logits.
// ---------------------------------------------------------------------------
__global__ __launch_bounds__(256) void k5_bn_relu_logits_loss(
    const float* __restrict__ hmat, const float* __restrict__ scale,
    const float* __restrict__ shift, const float* __restrict__ W2,
    const float* __restrict__ b2, const float* __restrict__ labels,
    float* __restrict__ out)
{
    const int tid  = threadIdx.x;
    const int w    = tid >> 6;
    const int lane = tid & 63;
    const int b0   = blockIdx.x * 64 + w * 16;

    const int j0 = lane, j1 = lane + 64, j2 = lane + 128, j3 = lane + 192;
    const float sc0 = scale[j0], sc1 = scale[j1], sc2 = scale[j2], sc3 = scale[j3];
    const float sh0 = shift[j0], sh1 = shift[j1], sh2 = shift[j2], sh3 = shift[j3];
    const float w0 = W2[j0], w1 = W2[j1], w2v = W2[j2], w3 = W2[j3];
    const float bias2 = b2[0];

    float bce_acc = 0.f;
    for (int rr = 0; rr < 16; ++rr) {
        const int b = b0 + rr;
        const float* hr = hmat + (size_t)b * HID;
        float s = 0.f;
        s += fmaxf(fmaf(hr[j0], sc0, sh0), 0.f) * w0;
        s += fmaxf(fmaf(hr[j1], sc1, sh1), 0.f) * w1;
        s += fmaxf(fmaf(hr[j2], sc2, sh2), 0.f) * w2v;
        s += fmaxf(fmaf(hr[j3], sc3, sh3), 0.f) * w3;
#pragma unroll
        for (int off = 32; off > 0; off >>= 1)
            s += __shfl_down(s, off, 64);
        if (lane == 0) {
            float z = s + bias2;
            out[1 + b] = z;
            float lb = labels[b];
            bce_acc += fmaxf(z, 0.f) - z * lb + log1pf(expf(-fabsf(z)));
        }
    }
    if (lane == 0) atomicAdd(&out[0], bce_acc * (1.f / BATCH));
}

// ---------------------------------------------------------------------------
extern "C" void kernel_launch(void* const* d_in, const int* in_sizes, int n_in,
                              void* d_out, int out_size, void* d_ws, size_t ws_size,
                              hipStream_t stream)
{
    const int*   token_ids   = (const int*)d_in[0];
    const int*   segment_ids = (const int*)d_in[1];
    const float* labels      = (const float*)d_in[2];
    const float* emb         = (const float*)d_in[3];
    const float* W1          = (const float*)d_in[4];
    const float* b1          = (const float*)d_in[5];
    const float* gamma       = (const float*)d_in[6];
    const float* beta        = (const float*)d_in[7];
    const float* W2          = (const float*)d_in[8];
    const float* b2          = (const float*)d_in[9];
    float* out = (float*)d_out;
    float* ws  = (float*)d_ws;

    float* seg_sum = ws + WS_SEGSUM;   // reused as h after k2
    float* counts  = ws + WS_COUNTS;
    float* colsum  = ws + WS_COLSUM;
    float* colsq   = ws + WS_COLSQ;
    float* scale   = ws + WS_SCALE;
    float* shift   = ws + WS_SHIFT;

    const int T = in_sizes[0];

    hipMemsetAsync(d_ws, 0, (size_t)WS_ZERO_FLOATS * sizeof(float), stream);
    hipMemsetAsync(d_out, 0, sizeof(float), stream);  // loss accumulator

    const int g1 = (T + TPB1 - 1) / TPB1;
    k1_gather_segsum<<<g1, 256, 0, stream>>>(token_ids, segment_ids, emb,
                                             seg_sum, counts, T);
    k2_gemm_bn_partial<<<BATCH / ROWS2, 256, 0, stream>>>(
        seg_sum, counts, W1, b1, /*hout=*/seg_sum, colsum, colsq);
    k4_finalize<<<1, HID, 0, stream>>>(colsum, colsq, gamma, beta, scale, shift);
    k5_bn_relu_logits_loss<<<BATCH / 64, 256, 0, stream>>>(
        seg_sum, scale, shift, W2, b2, labels, out);
}

// Round 2
// 312.611 us; speedup vs baseline: 1.3476x; 1.3476x over previous
//
#include <hip/hip_runtime.h>
#include <math.h>

#define VOCAB 100000
#define HID 256
#define BATCH 4096
#define BN_EPS 1e-5f
#define TPB1 512      // tokens per block in k1 (4 waves x 128 tokens)
#define ROWS2 8       // batch rows per block in k2

// ws layout (in floats)
#define WS_SEGSUM 0
#define WS_COUNTS (BATCH * HID)            // 1048576
#define WS_COLSUM (WS_COUNTS + BATCH)      // +4096
#define WS_COLSQ  (WS_COLSUM + HID)
#define WS_ZERO_FLOATS (WS_COLSQ + HID)    // zero: seg_sum, counts, colsum, colsq

// ---------------------------------------------------------------------------
// k1: ragged embedding gather + segment sum + counts.
// Each wave owns a contiguous 128-token sub-range; lane owns 4 hidden columns
// (float4 -> 1 KB per wave-load). 4 independent token loads batched per
// iteration for memory-level parallelism. segment_ids sorted -> accumulate
// runs in registers, flush via atomicAdd at run boundaries only.
// ---------------------------------------------------------------------------
__global__ __launch_bounds__(256) void k1_gather_segsum(
    const int* __restrict__ token_ids, const int* __restrict__ segment_ids,
    const float* __restrict__ emb, float* __restrict__ seg_sum,
    float* __restrict__ counts, int T)
{
    __shared__ int s_tok[TPB1];
    __shared__ int s_seg[TPB1];
    const int tid  = threadIdx.x;
    const int t0   = blockIdx.x * TPB1;
    const int n    = min(TPB1, T - t0);
    if (n <= 0) return;
    for (int i = tid; i < n; i += 256) {
        s_tok[i] = token_ids[t0 + i];
        s_seg[i] = segment_ids[t0 + i];
    }
    __syncthreads();

    const int wave = tid >> 6;
    const int lane = tid & 63;
    const int per  = TPB1 / 4;                  // 128 tokens per wave
    const int start = wave * per;
    const int end   = min(start + per, n);
    if (start >= end) return;

    const float4* __restrict__ embv = reinterpret_cast<const float4*>(emb);
    float4 acc = make_float4(0.f, 0.f, 0.f, 0.f);
    int cur = s_seg[start];
    int runlen = 0;

#define K1_FLUSH() do {                                                        \
        float* p = &seg_sum[(size_t)cur * HID + lane * 4];                     \
        atomicAdd(p + 0, acc.x); atomicAdd(p + 1, acc.y);                      \
        atomicAdd(p + 2, acc.z); atomicAdd(p + 3, acc.w);                      \
        if (lane == 0) atomicAdd(&counts[cur], (float)runlen);                 \
        acc = make_float4(0.f, 0.f, 0.f, 0.f); runlen = 0;                     \
    } while (0)

#define K1_PROC(ii, v) do {                                                    \
        int seg = s_seg[ii];               /* LDS broadcast, wave-uniform */   \
        if (seg != cur) { K1_FLUSH(); cur = seg; }                             \
        acc.x += (v).x; acc.y += (v).y; acc.z += (v).z; acc.w += (v).w;        \
        runlen++;                                                              \
    } while (0)

    const int m4 = start + ((end - start) & ~3);
    for (int i = start; i < m4; i += 4) {
        // 4 independent 16B loads in flight before any processing
        float4 a0 = embv[(size_t)s_tok[i + 0] * (HID / 4) + lane];
        float4 a1 = embv[(size_t)s_tok[i + 1] * (HID / 4) + lane];
        float4 a2 = embv[(size_t)s_tok[i + 2] * (HID / 4) + lane];
        float4 a3 = embv[(size_t)s_tok[i + 3] * (HID / 4) + lane];
        K1_PROC(i + 0, a0);
        K1_PROC(i + 1, a1);
        K1_PROC(i + 2, a2);
        K1_PROC(i + 3, a3);
    }
    for (int i = m4; i < end; ++i) {
        float4 a = embv[(size_t)s_tok[i] * (HID / 4) + lane];
        K1_PROC(i, a);
    }
    K1_FLUSH();
#undef K1_PROC
#undef K1_FLUSH
}

// ---------------------------------------------------------------------------
// k2: h = (seg_sum/max(counts,1)) @ W1^T + b1, fused with BN column partials.
// 8-row tile in LDS (512 blocks -> 2 blocks/CU for latency hiding on the
// uncoalesced W1 reads). hout aliases seg_sum (safe: tile staged to LDS
// before writes; each row touched by exactly one block).
// Block 0 thread 0 also zeroes out[0] (loss accumulator) for k5.
// ---------------------------------------------------------------------------
__global__ __launch_bounds__(256) void k2_gemm_bn_partial(
    const float* seg_sum, const float* __restrict__ counts,
    const float* __restrict__ W1, const float* __restrict__ b1,
    float* hout, float* __restrict__ colsum, float* __restrict__ colsq,
    float* __restrict__ out)
{
    __shared__ float s_bow[ROWS2][HID];
    const int tid = threadIdx.x;
    const int b0  = blockIdx.x * ROWS2;

    if (blockIdx.x == 0 && tid == 0) out[0] = 0.f;   // k5 runs after k2

#pragma unroll
    for (int r = 0; r < ROWS2; ++r) {
        float c   = counts[b0 + r];
        float inv = 1.f / fmaxf(c, 1.f);
        s_bow[r][tid] = seg_sum[(size_t)(b0 + r) * HID + tid] * inv;
    }
    __syncthreads();

    const int j = tid;
    float acc[ROWS2];
    const float bj = b1[j];
#pragma unroll
    for (int r = 0; r < ROWS2; ++r) acc[r] = bj;

    const float4* W1v = reinterpret_cast<const float4*>(W1 + (size_t)j * HID);
#pragma unroll 4
    for (int k4 = 0; k4 < HID / 4; ++k4) {
        float4 w = W1v[k4];
#pragma unroll
        for (int r = 0; r < ROWS2; ++r) {
            const float4* bv = reinterpret_cast<const float4*>(&s_bow[r][0]);
            float4 bb = bv[k4];          // ds_read_b128, broadcast (same addr)
            acc[r] = fmaf(bb.x, w.x, acc[r]);
            acc[r] = fmaf(bb.y, w.y, acc[r]);
            acc[r] = fmaf(bb.z, w.z, acc[r]);
            acc[r] = fmaf(bb.w, w.w, acc[r]);
        }
    }

    float ls = 0.f, lq = 0.f;
#pragma unroll
    for (int r = 0; r < ROWS2; ++r) {
        float v = acc[r];
        hout[(size_t)(b0 + r) * HID + j] = v;   // coalesced
        ls += v;
        lq += v * v;
    }
    atomicAdd(&colsum[j], ls);
    atomicAdd(&colsq[j], lq);
}

// ---------------------------------------------------------------------------
// k5: BN finalize (folded) + apply + ReLU + logits (dot with W2) + BCE loss.
// 256 blocks; one 64-lane wave per 4 rows. Per-block LDS loss reduction ->
// one atomicAdd into out[0] per block.
// out[0] = loss, out[1..BATCH] = logits.
// ---------------------------------------------------------------------------
__global__ __launch_bounds__(256) void k5_bn_relu_logits_loss(
    const float* __restrict__ hmat,
    const float* __restrict__ colsum, const float* __restrict__ colsq,
    const float* __restrict__ gamma, const float* __restrict__ beta,
    const float* __restrict__ W2, const float* __restrict__ b2,
    const float* __restrict__ labels, float* __restrict__ out)
{
    __shared__ float s_loss[4];
    const int tid  = threadIdx.x;
    const int w    = tid >> 6;
    const int lane = tid & 63;
    const int b0   = blockIdx.x * 16 + w * 4;

    const int j0 = lane, j1 = lane + 64, j2 = lane + 128, j3 = lane + 192;

    // BN finalize per column (was k4): scale = gamma*rsqrt(var+eps),
    // shift = beta - mu*scale
#define BN_SS(jj, sc, sh) \
    { float mu = colsum[jj] * (1.f / BATCH); \
      float vr = colsq[jj] * (1.f / BATCH) - mu * mu; \
      sc = gamma[jj] * rsqrtf(vr + BN_EPS); \
      sh = beta[jj] - mu * sc; }
    float sc0, sh0, sc1, sh1, sc2, sh2, sc3, sh3;
    BN_SS(j0, sc0, sh0); BN_SS(j1, sc1, sh1);
    BN_SS(j2, sc2, sh2); BN_SS(j3, sc3, sh3);
#undef BN_SS

    const float w0 = W2[j0], w1 = W2[j1], w2v = W2[j2], w3 = W2[j3];
    const float bias2 = b2[0];

    float bce_acc = 0.f;
#pragma unroll
    for (int rr = 0; rr < 4; ++rr) {
        const int b = b0 + rr;
        const float* hr = hmat + (size_t)b * HID;
        float h0 = hr[j0], h1 = hr[j1], h2 = hr[j2], h3 = hr[j3];
        float s = 0.f;
        s += fmaxf(fmaf(h0, sc0, sh0), 0.f) * w0;
        s += fmaxf(fmaf(h1, sc1, sh1), 0.f) * w1;
        s += fmaxf(fmaf(h2, sc2, sh2), 0.f) * w2v;
        s += fmaxf(fmaf(h3, sc3, sh3), 0.f) * w3;
#pragma unroll
        for (int off = 32; off > 0; off >>= 1)
            s += __shfl_down(s, off, 64);
        if (lane == 0) {
            float z = s + bias2;
            out[1 + b] = z;
            float lb = labels[b];
            bce_acc += fmaxf(z, 0.f) - z * lb + log1pf(expf(-fabsf(z)));
        }
    }
    if (lane == 0) s_loss[w] = bce_acc;
    __syncthreads();
    if (tid == 0) {
        float t = (s_loss[0] + s_loss[1]) + (s_loss[2] + s_loss[3]);
        atomicAdd(&out[0], t * (1.f / BATCH));
    }
}

// ---------------------------------------------------------------------------
extern "C" void kernel_launch(void* const* d_in, const int* in_sizes, int n_in,
                              void* d_out, int out_size, void* d_ws, size_t ws_size,
                              hipStream_t stream)
{
    const int*   token_ids   = (const int*)d_in[0];
    const int*   segment_ids = (const int*)d_in[1];
    const float* labels      = (const float*)d_in[2];
    const float* emb         = (const float*)d_in[3];
    const float* W1          = (const float*)d_in[4];
    const float* b1          = (const float*)d_in[5];
    const float* gamma       = (const float*)d_in[6];
    const float* beta        = (const float*)d_in[7];
    const float* W2          = (const float*)d_in[8];
    const float* b2          = (const float*)d_in[9];
    float* out = (float*)d_out;
    float* ws  = (float*)d_ws;

    float* seg_sum = ws + WS_SEGSUM;   // reused as h after k2
    float* counts  = ws + WS_COUNTS;
    float* colsum  = ws + WS_COLSUM;
    float* colsq   = ws + WS_COLSQ;

    const int T = in_sizes[0];

    hipMemsetAsync(d_ws, 0, (size_t)WS_ZERO_FLOATS * sizeof(float), stream);

    const int g1 = (T + TPB1 - 1) / TPB1;
    k1_gather_segsum<<<g1, 256, 0, stream>>>(token_ids, segment_ids, emb,
                                             seg_sum, counts, T);
    k2_gemm_bn_partial<<<BATCH / ROWS2, 256, 0, stream>>>(
        seg_sum, counts, W1, b1, /*hout=*/seg_sum, colsum, colsq, out);
    k5_bn_relu_logits_loss<<<BATCH / 16, 256, 0, stream>>>(
        seg_sum, colsum, colsq, gamma, beta, W2, b2, labels, out);
}

// Round 3
// 284.230 us; speedup vs baseline: 1.4821x; 1.0999x over previous
//
#include <hip/hip_runtime.h>
#include <hip/hip_fp16.h>
#include <math.h>

#define VOCAB 100000
#define HID 256
#define BATCH 4096
#define BN_EPS 1e-5f
#define TPB1 512      // tokens per block in k1 (4 waves x 128 tokens)
#define ROWS2 8       // batch rows per block in k2
#define KT 16         // k-tile width in k2

// ws layout (in floats)
#define WS_SEGSUM 0
#define WS_COUNTS (BATCH * HID)            // 1048576
#define WS_COLSUM (WS_COUNTS + BATCH)
#define WS_COLSQ  (WS_COLSUM + HID)
#define WS_ZERO_FLOATS (WS_COLSQ + HID)    // zero: seg_sum, counts, colsum, colsq
#define WS_EMB16_OFF_BYTES ((size_t)WS_ZERO_FLOATS * 4)   // 16B-aligned
#define WS_FP16_BYTES_NEEDED (WS_EMB16_OFF_BYTES + (size_t)VOCAB * HID * 2)

// ---------------------------------------------------------------------------
// k0: emb fp32 -> fp16 table in ws. Streaming, fully coalesced.
// ---------------------------------------------------------------------------
__global__ __launch_bounds__(256) void k0_convert(
    const float* __restrict__ emb, __half* __restrict__ emb16, int n4)
{
    int i = blockIdx.x * 256 + threadIdx.x;
    if (i >= n4) return;
    float4 v = reinterpret_cast<const float4*>(emb)[i];
    __half2 a = __halves2half2(__float2half_rn(v.x), __float2half_rn(v.y));
    __half2 b = __halves2half2(__float2half_rn(v.z), __float2half_rn(v.w));
    uint2 o;
    o.x = __builtin_bit_cast(unsigned int, a);
    o.y = __builtin_bit_cast(unsigned int, b);
    reinterpret_cast<uint2*>(emb16)[i] = o;
}

// ---------------------------------------------------------------------------
// k1 (fp16 table): ragged gather + segment sum + counts. Wave owns 128
// contiguous tokens; lane owns 4 hidden columns (uint2 = 4 halves = 8B/lane,
// 512B per wave-load). 8 independent token loads batched per iteration.
// Sorted segment_ids -> register run accumulation, atomic flush at run ends.
// ---------------------------------------------------------------------------
__global__ __launch_bounds__(256) void k1_gather_fp16(
    const int* __restrict__ token_ids, const int* __restrict__ segment_ids,
    const __half* __restrict__ emb16, float* __restrict__ seg_sum,
    float* __restrict__ counts, int T)
{
    __shared__ int s_tok[TPB1];
    __shared__ int s_seg[TPB1];
    const int tid = threadIdx.x;
    const int t0  = blockIdx.x * TPB1;
    const int n   = min(TPB1, T - t0);
    if (n <= 0) return;
    for (int i = tid; i < n; i += 256) {
        s_tok[i] = token_ids[t0 + i];
        s_seg[i] = segment_ids[t0 + i];
    }
    __syncthreads();

    const int wave = tid >> 6;
    const int lane = tid & 63;
    const int per  = TPB1 / 4;
    const int start = wave * per;
    const int end   = min(start + per, n);
    if (start >= end) return;

    const uint2* __restrict__ embv = reinterpret_cast<const uint2*>(emb16);
    float4 acc = make_float4(0.f, 0.f, 0.f, 0.f);
    int cur = s_seg[start];
    int runlen = 0;

#define K1_FLUSH() do {                                                        \
        float* p = &seg_sum[(size_t)cur * HID + lane * 4];                     \
        atomicAdd(p + 0, acc.x); atomicAdd(p + 1, acc.y);                      \
        atomicAdd(p + 2, acc.z); atomicAdd(p + 3, acc.w);                      \
        if (lane == 0) atomicAdd(&counts[cur], (float)runlen);                 \
        acc = make_float4(0.f, 0.f, 0.f, 0.f); runlen = 0;                     \
    } while (0)

#define K1_PROC16(ii, u) do {                                                  \
        int seg = s_seg[ii];               /* LDS broadcast, wave-uniform */   \
        if (seg != cur) { K1_FLUSH(); cur = seg; }                             \
        __half2 h01 = __builtin_bit_cast(__half2, (u).x);                      \
        __half2 h23 = __builtin_bit_cast(__half2, (u).y);                      \
        float2 f01 = __half22float2(h01);                                      \
        float2 f23 = __half22float2(h23);                                      \
        acc.x += f01.x; acc.y += f01.y; acc.z += f23.x; acc.w += f23.y;        \
        runlen++;                                                              \
    } while (0)

    const int m8 = start + ((end - start) & ~7);
    for (int i = start; i < m8; i += 8) {
        uint2 u0 = embv[(size_t)s_tok[i + 0] * 64 + lane];
        uint2 u1 = embv[(size_t)s_tok[i + 1] * 64 + lane];
        uint2 u2 = embv[(size_t)s_tok[i + 2] * 64 + lane];
        uint2 u3 = embv[(size_t)s_tok[i + 3] * 64 + lane];
        uint2 u4 = embv[(size_t)s_tok[i + 4] * 64 + lane];
        uint2 u5 = embv[(size_t)s_tok[i + 5] * 64 + lane];
        uint2 u6 = embv[(size_t)s_tok[i + 6] * 64 + lane];
        uint2 u7 = embv[(size_t)s_tok[i + 7] * 64 + lane];
        K1_PROC16(i + 0, u0); K1_PROC16(i + 1, u1);
        K1_PROC16(i + 2, u2); K1_PROC16(i + 3, u3);
        K1_PROC16(i + 4, u4); K1_PROC16(i + 5, u5);
        K1_PROC16(i + 6, u6); K1_PROC16(i + 7, u7);
    }
    for (int i = m8; i < end; ++i) {
        uint2 u = embv[(size_t)s_tok[i] * 64 + lane];
        K1_PROC16(i, u);
    }
    K1_FLUSH();
#undef K1_PROC16
#undef K1_FLUSH
}

// ---------------------------------------------------------------------------
// k1 (fp32 fallback, used only if ws_size too small for the fp16 table).
// ---------------------------------------------------------------------------
__global__ __launch_bounds__(256) void k1_gather_fp32(
    const int* __restrict__ token_ids, const int* __restrict__ segment_ids,
    const float* __restrict__ emb, float* __restrict__ seg_sum,
    float* __restrict__ counts, int T)
{
    __shared__ int s_tok[TPB1];
    __shared__ int s_seg[TPB1];
    const int tid = threadIdx.x;
    const int t0  = blockIdx.x * TPB1;
    const int n   = min(TPB1, T - t0);
    if (n <= 0) return;
    for (int i = tid; i < n; i += 256) {
        s_tok[i] = token_ids[t0 + i];
        s_seg[i] = segment_ids[t0 + i];
    }
    __syncthreads();

    const int wave = tid >> 6;
    const int lane = tid & 63;
    const int per  = TPB1 / 4;
    const int start = wave * per;
    const int end   = min(start + per, n);
    if (start >= end) return;

    const float4* __restrict__ embv = reinterpret_cast<const float4*>(emb);
    float4 acc = make_float4(0.f, 0.f, 0.f, 0.f);
    int cur = s_seg[start];
    int runlen = 0;

#define K1_FLUSH() do {                                                        \
        float* p = &seg_sum[(size_t)cur * HID + lane * 4];                     \
        atomicAdd(p + 0, acc.x); atomicAdd(p + 1, acc.y);                      \
        atomicAdd(p + 2, acc.z); atomicAdd(p + 3, acc.w);                      \
        if (lane == 0) atomicAdd(&counts[cur], (float)runlen);                 \
        acc = make_float4(0.f, 0.f, 0.f, 0.f); runlen = 0;                     \
    } while (0)

#define K1_PROC(ii, v) do {                                                    \
        int seg = s_seg[ii];                                                   \
        if (seg != cur) { K1_FLUSH(); cur = seg; }                             \
        acc.x += (v).x; acc.y += (v).y; acc.z += (v).z; acc.w += (v).w;        \
        runlen++;                                                              \
    } while (0)

    const int m4 = start + ((end - start) & ~3);
    for (int i = start; i < m4; i += 4) {
        float4 a0 = embv[(size_t)s_tok[i + 0] * 64 + lane];
        float4 a1 = embv[(size_t)s_tok[i + 1] * 64 + lane];
        float4 a2 = embv[(size_t)s_tok[i + 2] * 64 + lane];
        float4 a3 = embv[(size_t)s_tok[i + 3] * 64 + lane];
        K1_PROC(i + 0, a0); K1_PROC(i + 1, a1);
        K1_PROC(i + 2, a2); K1_PROC(i + 3, a3);
    }
    for (int i = m4; i < end; ++i) {
        float4 a = embv[(size_t)s_tok[i] * 64 + lane];
        K1_PROC(i, a);
    }
    K1_FLUSH();
#undef K1_PROC
#undef K1_FLUSH
}

// ---------------------------------------------------------------------------
// k2: h = (seg_sum/max(counts,1)) @ W1^T + b1, fused BN column partials.
// W1 staged per 16-k tile into LDS TRANSPOSED (s_w1t[kk][j], padded) with
// coalesced global loads (16 consecutive floats per row chunk) and register
// prefetch double-buffering. Compute reads: stride-1 LDS (2 lanes/bank =
// free) for W, broadcast b128 for bow. hout aliases seg_sum (rows staged to
// LDS first; blocks own disjoint rows).
// ---------------------------------------------------------------------------
__global__ __launch_bounds__(256) void k2_gemm_bn_partial(
    const float* seg_sum, const float* __restrict__ counts,
    const float* __restrict__ W1, const float* __restrict__ b1,
    float* hout, float* __restrict__ colsum, float* __restrict__ colsq,
    float* __restrict__ out)
{
    __shared__ float s_bow[ROWS2][HID];
    __shared__ float s_w1t[KT][HID + 1];
    const int tid = threadIdx.x;
    const int b0  = blockIdx.x * ROWS2;

    if (blockIdx.x == 0 && tid == 0) out[0] = 0.f;   // k5 runs after k2

#pragma unroll
    for (int r = 0; r < ROWS2; ++r) {
        float c   = counts[b0 + r];
        float inv = 1.f / fmaxf(c, 1.f);
        s_bow[r][tid] = seg_sum[(size_t)(b0 + r) * HID + tid] * inv;
    }

    const int jrow = tid >> 2;   // 0..63 (row within 64-row group)
    const int kq   = tid & 3;    // which float4 of the 16-wide k tile
    const float4* __restrict__ W1v4 = reinterpret_cast<const float4*>(W1);

    float acc[ROWS2];
    const float bj = b1[tid];
#pragma unroll
    for (int r = 0; r < ROWS2; ++r) acc[r] = bj;

    // prefetch tile 0: pre[p] = W1[p*64+jrow][0*16 + kq*4 .. +3]
    float4 pre[4];
#pragma unroll
    for (int p = 0; p < 4; ++p)
        pre[p] = W1v4[(size_t)(p * 64 + jrow) * 64 + kq];

    for (int kt = 0; kt < HID / KT; ++kt) {
        __syncthreads();   // prev tile compute done (and s_bow ready at kt=0)
#pragma unroll
        for (int p = 0; p < 4; ++p) {
            int j = p * 64 + jrow;
            s_w1t[kq * 4 + 0][j] = pre[p].x;
            s_w1t[kq * 4 + 1][j] = pre[p].y;
            s_w1t[kq * 4 + 2][j] = pre[p].z;
            s_w1t[kq * 4 + 3][j] = pre[p].w;
        }
        __syncthreads();
        if (kt + 1 < HID / KT) {
#pragma unroll
            for (int p = 0; p < 4; ++p)
                pre[p] = W1v4[(size_t)(p * 64 + jrow) * 64 + (kt + 1) * 4 + kq];
        }
#pragma unroll
        for (int q = 0; q < 4; ++q) {
            float w0 = s_w1t[q * 4 + 0][tid];
            float w1 = s_w1t[q * 4 + 1][tid];
            float w2 = s_w1t[q * 4 + 2][tid];
            float w3 = s_w1t[q * 4 + 3][tid];
#pragma unroll
            for (int r = 0; r < ROWS2; ++r) {
                float4 bb = *reinterpret_cast<const float4*>(
                    &s_bow[r][kt * KT + q * 4]);   // broadcast b128
                acc[r] = fmaf(bb.x, w0,
                         fmaf(bb.y, w1,
                         fmaf(bb.z, w2,
                         fmaf(bb.w, w3, acc[r]))));
            }
        }
    }

    float ls = 0.f, lq = 0.f;
#pragma unroll
    for (int r = 0; r < ROWS2; ++r) {
        float v = acc[r];
        hout[(size_t)(b0 + r) * HID + tid] = v;   // coalesced
        ls += v;
        lq += v * v;
    }
    atomicAdd(&colsum[tid], ls);
    atomicAdd(&colsq[tid], lq);
}

// ---------------------------------------------------------------------------
// k5: BN finalize (folded) + apply + ReLU + logits + BCE loss.
// 256 blocks; one wave per 4 rows; per-block LDS loss reduction.
// out[0] = loss, out[1..BATCH] = logits.
// ---------------------------------------------------------------------------
__global__ __launch_bounds__(256) void k5_bn_relu_logits_loss(
    const float* __restrict__ hmat,
    const float* __restrict__ colsum, const float* __restrict__ colsq,
    const float* __restrict__ gamma, const float* __restrict__ beta,
    const float* __restrict__ W2, const float* __restrict__ b2,
    const float* __restrict__ labels, float* __restrict__ out)
{
    __shared__ float s_loss[4];
    const int tid  = threadIdx.x;
    const int w    = tid >> 6;
    const int lane = tid & 63;
    const int b0   = blockIdx.x * 16 + w * 4;

    const int j0 = lane, j1 = lane + 64, j2 = lane + 128, j3 = lane + 192;

#define BN_SS(jj, sc, sh) \
    { float mu = colsum[jj] * (1.f / BATCH); \
      float vr = colsq[jj] * (1.f / BATCH) - mu * mu; \
      sc = gamma[jj] * rsqrtf(vr + BN_EPS); \
      sh = beta[jj] - mu * sc; }
    float sc0, sh0, sc1, sh1, sc2, sh2, sc3, sh3;
    BN_SS(j0, sc0, sh0); BN_SS(j1, sc1, sh1);
    BN_SS(j2, sc2, sh2); BN_SS(j3, sc3, sh3);
#undef BN_SS

    const float w0 = W2[j0], w1 = W2[j1], w2v = W2[j2], w3 = W2[j3];
    const float bias2 = b2[0];

    float bce_acc = 0.f;
#pragma unroll
    for (int rr = 0; rr < 4; ++rr) {
        const int b = b0 + rr;
        const float* hr = hmat + (size_t)b * HID;
        float h0 = hr[j0], h1 = hr[j1], h2 = hr[j2], h3 = hr[j3];
        float s = 0.f;
        s += fmaxf(fmaf(h0, sc0, sh0), 0.f) * w0;
        s += fmaxf(fmaf(h1, sc1, sh1), 0.f) * w1;
        s += fmaxf(fmaf(h2, sc2, sh2), 0.f) * w2v;
        s += fmaxf(fmaf(h3, sc3, sh3), 0.f) * w3;
#pragma unroll
        for (int off = 32; off > 0; off >>= 1)
            s += __shfl_down(s, off, 64);
        if (lane == 0) {
            float z = s + bias2;
            out[1 + b] = z;
            float lb = labels[b];
            bce_acc += fmaxf(z, 0.f) - z * lb + log1pf(expf(-fabsf(z)));
        }
    }
    if (lane == 0) s_loss[w] = bce_acc;
    __syncthreads();
    if (tid == 0) {
        float t = (s_loss[0] + s_loss[1]) + (s_loss[2] + s_loss[3]);
        atomicAdd(&out[0], t * (1.f / BATCH));
    }
}

// ---------------------------------------------------------------------------
extern "C" void kernel_launch(void* const* d_in, const int* in_sizes, int n_in,
                              void* d_out, int out_size, void* d_ws, size_t ws_size,
                              hipStream_t stream)
{
    const int*   token_ids   = (const int*)d_in[0];
    const int*   segment_ids = (const int*)d_in[1];
    const float* labels      = (const float*)d_in[2];
    const float* emb         = (const float*)d_in[3];
    const float* W1          = (const float*)d_in[4];
    const float* b1          = (const float*)d_in[5];
    const float* gamma       = (const float*)d_in[6];
    const float* beta        = (const float*)d_in[7];
    const float* W2          = (const float*)d_in[8];
    const float* b2          = (const float*)d_in[9];
    float* out = (float*)d_out;
    float* ws  = (float*)d_ws;

    float* seg_sum = ws + WS_SEGSUM;   // reused as h after k2
    float* counts  = ws + WS_COUNTS;
    float* colsum  = ws + WS_COLSUM;
    float* colsq   = ws + WS_COLSQ;

    const int T = in_sizes[0];
    const int g1 = (T + TPB1 - 1) / TPB1;

    hipMemsetAsync(d_ws, 0, (size_t)WS_ZERO_FLOATS * sizeof(float), stream);

    if (ws_size >= WS_FP16_BYTES_NEEDED) {
        __half* emb16 = (__half*)((char*)d_ws + WS_EMB16_OFF_BYTES);
        const int n4 = VOCAB * HID / 4;
        k0_convert<<<(n4 + 255) / 256, 256, 0, stream>>>(emb, emb16, n4);
        k1_gather_fp16<<<g1, 256, 0, stream>>>(token_ids, segment_ids, emb16,
                                               seg_sum, counts, T);
    } else {
        k1_gather_fp32<<<g1, 256, 0, stream>>>(token_ids, segment_ids, emb,
                                               seg_sum, counts, T);
    }
    k2_gemm_bn_partial<<<BATCH / ROWS2, 256, 0, stream>>>(
        seg_sum, counts, W1, b1, /*hout=*/seg_sum, colsum, colsq, out);
    k5_bn_relu_logits_loss<<<BATCH / 16, 256, 0, stream>>>(
        seg_sum, colsum, colsq, gamma, beta, W2, b2, labels, out);
}

// Round 4
// 280.577 us; speedup vs baseline: 1.5014x; 1.0130x over previous
//
#include <hip/hip_runtime.h>
#include <hip/hip_fp16.h>
#include <math.h>

#define VOCAB 100000
#define HID 256
#define BATCH 4096
#define BN_EPS 1e-5f
#define TPB1 512      // tokens per block in k1 (4 waves x 128 tokens)

// ws layout (in floats)
#define WS_SEGSUM 0
#define WS_COUNTS (BATCH * HID)            // 1048576
#define WS_COLSUM (WS_COUNTS + BATCH)
#define WS_COLSQ  (WS_COLSUM + HID)
#define WS_ZERO_FLOATS (WS_COLSQ + HID)    // 1053184 floats; zero-filled by k0
#define WS_EMB16_OFF_BYTES ((size_t)WS_ZERO_FLOATS * 4)   // 16B-aligned
#define WS_FP16_BYTES_NEEDED (WS_EMB16_OFF_BYTES + (size_t)VOCAB * HID * 2)

// ---------------------------------------------------------------------------
// k0: emb fp32 -> fp16 table in ws; also zeroes the accumulator region
// (seg_sum/counts/colsum/colsq) so no separate memset dispatch is needed.
// ---------------------------------------------------------------------------
__global__ __launch_bounds__(256) void k0_convert_zero(
    const float* __restrict__ emb, __half* __restrict__ emb16,
    float4* __restrict__ zws, int n4, int nz4)
{
    int i = blockIdx.x * 256 + threadIdx.x;
    if (i < nz4) zws[i] = make_float4(0.f, 0.f, 0.f, 0.f);
    if (i >= n4) return;
    float4 v = reinterpret_cast<const float4*>(emb)[i];
    __half2 a = __halves2half2(__float2half_rn(v.x), __float2half_rn(v.y));
    __half2 b = __halves2half2(__float2half_rn(v.z), __float2half_rn(v.w));
    uint2 o;
    o.x = __builtin_bit_cast(unsigned int, a);
    o.y = __builtin_bit_cast(unsigned int, b);
    reinterpret_cast<uint2*>(emb16)[i] = o;
}

// ---------------------------------------------------------------------------
// k1 (fp16 table): ragged gather + segment sum + counts. Wave owns 128
// contiguous tokens; lane owns 4 hidden columns (8B/lane, 512B/wave-load).
// 8 independent token loads in flight. Sorted segment_ids -> register run
// accumulation, atomic flush at run boundaries. At byte-roofline (~5.7 TB/s
// demand incl. L3-served re-reads) as of round 3.
// ---------------------------------------------------------------------------
__global__ __launch_bounds__(256) void k1_gather_fp16(
    const int* __restrict__ token_ids, const int* __restrict__ segment_ids,
    const __half* __restrict__ emb16, float* __restrict__ seg_sum,
    float* __restrict__ counts, int T)
{
    __shared__ int s_tok[TPB1];
    __shared__ int s_seg[TPB1];
    const int tid = threadIdx.x;
    const int t0  = blockIdx.x * TPB1;
    const int n   = min(TPB1, T - t0);
    if (n <= 0) return;
    for (int i = tid; i < n; i += 256) {
        s_tok[i] = token_ids[t0 + i];
        s_seg[i] = segment_ids[t0 + i];
    }
    __syncthreads();

    const int wave = tid >> 6;
    const int lane = tid & 63;
    const int per  = TPB1 / 4;
    const int start = wave * per;
    const int end   = min(start + per, n);
    if (start >= end) return;

    const uint2* __restrict__ embv = reinterpret_cast<const uint2*>(emb16);
    float4 acc = make_float4(0.f, 0.f, 0.f, 0.f);
    int cur = s_seg[start];
    int runlen = 0;

#define K1_FLUSH() do {                                                        \
        float* p = &seg_sum[(size_t)cur * HID + lane * 4];                     \
        atomicAdd(p + 0, acc.x); atomicAdd(p + 1, acc.y);                      \
        atomicAdd(p + 2, acc.z); atomicAdd(p + 3, acc.w);                      \
        if (lane == 0) atomicAdd(&counts[cur], (float)runlen);                 \
        acc = make_float4(0.f, 0.f, 0.f, 0.f); runlen = 0;                     \
    } while (0)

#define K1_PROC16(ii, u) do {                                                  \
        int seg = s_seg[ii];               /* LDS broadcast, wave-uniform */   \
        if (seg != cur) { K1_FLUSH(); cur = seg; }                             \
        __half2 h01 = __builtin_bit_cast(__half2, (u).x);                      \
        __half2 h23 = __builtin_bit_cast(__half2, (u).y);                      \
        float2 f01 = __half22float2(h01);                                      \
        float2 f23 = __half22float2(h23);                                      \
        acc.x += f01.x; acc.y += f01.y; acc.z += f23.x; acc.w += f23.y;        \
        runlen++;                                                              \
    } while (0)

    const int m8 = start + ((end - start) & ~7);
    for (int i = start; i < m8; i += 8) {
        uint2 u0 = embv[(size_t)s_tok[i + 0] * 64 + lane];
        uint2 u1 = embv[(size_t)s_tok[i + 1] * 64 + lane];
        uint2 u2 = embv[(size_t)s_tok[i + 2] * 64 + lane];
        uint2 u3 = embv[(size_t)s_tok[i + 3] * 64 + lane];
        uint2 u4 = embv[(size_t)s_tok[i + 4] * 64 + lane];
        uint2 u5 = embv[(size_t)s_tok[i + 5] * 64 + lane];
        uint2 u6 = embv[(size_t)s_tok[i + 6] * 64 + lane];
        uint2 u7 = embv[(size_t)s_tok[i + 7] * 64 + lane];
        K1_PROC16(i + 0, u0); K1_PROC16(i + 1, u1);
        K1_PROC16(i + 2, u2); K1_PROC16(i + 3, u3);
        K1_PROC16(i + 4, u4); K1_PROC16(i + 5, u5);
        K1_PROC16(i + 6, u6); K1_PROC16(i + 7, u7);
    }
    for (int i = m8; i < end; ++i) {
        uint2 u = embv[(size_t)s_tok[i] * 64 + lane];
        K1_PROC16(i, u);
    }
    K1_FLUSH();
#undef K1_PROC16
#undef K1_FLUSH
}

// ---------------------------------------------------------------------------
// k1 (fp32 fallback, only if ws too small for the fp16 table).
// ---------------------------------------------------------------------------
__global__ __launch_bounds__(256) void k1_gather_fp32(
    const int* __restrict__ token_ids, const int* __restrict__ segment_ids,
    const float* __restrict__ emb, float* __restrict__ seg_sum,
    float* __restrict__ counts, int T)
{
    __shared__ int s_tok[TPB1];
    __shared__ int s_seg[TPB1];
    const int tid = threadIdx.x;
    const int t0  = blockIdx.x * TPB1;
    const int n   = min(TPB1, T - t0);
    if (n <= 0) return;
    for (int i = tid; i < n; i += 256) {
        s_tok[i] = token_ids[t0 + i];
        s_seg[i] = segment_ids[t0 + i];
    }
    __syncthreads();

    const int wave = tid >> 6;
    const int lane = tid & 63;
    const int per  = TPB1 / 4;
    const int start = wave * per;
    const int end   = min(start + per, n);
    if (start >= end) return;

    const float4* __restrict__ embv = reinterpret_cast<const float4*>(emb);
    float4 acc = make_float4(0.f, 0.f, 0.f, 0.f);
    int cur = s_seg[start];
    int runlen = 0;

#define K1_FLUSH() do {                                                        \
        float* p = &seg_sum[(size_t)cur * HID + lane * 4];                     \
        atomicAdd(p + 0, acc.x); atomicAdd(p + 1, acc.y);                      \
        atomicAdd(p + 2, acc.z); atomicAdd(p + 3, acc.w);                      \
        if (lane == 0) atomicAdd(&counts[cur], (float)runlen);                 \
        acc = make_float4(0.f, 0.f, 0.f, 0.f); runlen = 0;                     \
    } while (0)

#define K1_PROC(ii, v) do {                                                    \
        int seg = s_seg[ii];                                                   \
        if (seg != cur) { K1_FLUSH(); cur = seg; }                             \
        acc.x += (v).x; acc.y += (v).y; acc.z += (v).z; acc.w += (v).w;        \
        runlen++;                                                              \
    } while (0)

    const int m4 = start + ((end - start) & ~3);
    for (int i = start; i < m4; i += 4) {
        float4 a0 = embv[(size_t)s_tok[i + 0] * 64 + lane];
        float4 a1 = embv[(size_t)s_tok[i + 1] * 64 + lane];
        float4 a2 = embv[(size_t)s_tok[i + 2] * 64 + lane];
        float4 a3 = embv[(size_t)s_tok[i + 3] * 64 + lane];
        K1_PROC(i + 0, a0); K1_PROC(i + 1, a1);
        K1_PROC(i + 2, a2); K1_PROC(i + 3, a3);
    }
    for (int i = m4; i < end; ++i) {
        float4 a = embv[(size_t)s_tok[i] * 64 + lane];
        K1_PROC(i, a);
    }
    K1_FLUSH();
#undef K1_PROC
#undef K1_FLUSH
}

// ---------------------------------------------------------------------------
// k2: h = (seg_sum/max(counts,1)) @ W1^T + b1, fused BN column partials.
// 256 blocks x 16 rows. Thread computes a 4-row x 4-col micro-tile:
// per 4-k step, 8 ds_read_b128 (4 broadcast bow + 4 contiguous W1t) feed
// 64 FMAs -> compute-bound, not DS-bound. W1 staged per 32-k tile into LDS
// transposed (+1 pad -> <=2-way on writes), coalesced 128B-chunk global
// loads, register prefetch of the next tile. Block-level LDS reduction for
// colsum/colsq -> 1 global atomic per column per block.
// hout aliases seg_sum (rows staged to LDS first; blocks own disjoint rows).
// ---------------------------------------------------------------------------
#define KT2 32
__global__ __launch_bounds__(256) void k2_gemm_bn(
    const float* seg_sum, const float* __restrict__ counts,
    const float* __restrict__ W1, const float* __restrict__ b1,
    float* hout, float* __restrict__ colsum, float* __restrict__ colsq,
    float* __restrict__ out)
{
    __shared__ float s_bow[16][HID];          // 16 KB
    __shared__ float s_w1t[KT2][HID + 1];     // ~33 KB, k-major transposed
    __shared__ float s_cs[HID];
    __shared__ float s_cq[HID];
    const int tid = threadIdx.x;
    const int b0  = blockIdx.x * 16;

    if (blockIdx.x == 0 && tid == 0) out[0] = 0.f;   // k5 runs after k2
    s_cs[tid] = 0.f;
    s_cq[tid] = 0.f;

    // stage bow (row-major), coalesced b128, divide by count on the way in
    const float4* ss4 = reinterpret_cast<const float4*>(seg_sum + (size_t)b0 * HID);
#pragma unroll
    for (int p = 0; p < 4; ++p) {
        int f  = p * 256 + tid;
        int r  = f >> 6, k4 = f & 63;
        float inv = 1.f / fmaxf(counts[b0 + r], 1.f);
        float4 v = ss4[f];
        v.x *= inv; v.y *= inv; v.z *= inv; v.w *= inv;
        *reinterpret_cast<float4*>(&s_bow[r][k4 * 4]) = v;
    }

    const int jr = tid >> 3;          // 0..31: row offset within 32-row group
    const int q  = tid & 7;           // 0..7: which float4 of the 32-k chunk
    const float4* __restrict__ W1v = reinterpret_cast<const float4*>(W1);

    // prefetch W1 tile 0: pre[pass] = W1[pass*32+jr][q*4 .. q*4+3]
    float4 pre[8];
#pragma unroll
    for (int pass = 0; pass < 8; ++pass)
        pre[pass] = W1v[(size_t)(pass * 32 + jr) * 64 + q];

    const int cg = tid & 63;          // col group: cols cg*4 .. cg*4+3
    const int rg = tid >> 6;          // row group: rows rg*4 .. rg*4+3

    float acc[4][4];
    {
        float4 bj = reinterpret_cast<const float4*>(b1)[cg];
#pragma unroll
        for (int r = 0; r < 4; ++r) {
            acc[r][0] = bj.x; acc[r][1] = bj.y;
            acc[r][2] = bj.z; acc[r][3] = bj.w;
        }
    }

    for (int kt = 0; kt < HID / KT2; ++kt) {
        __syncthreads();   // prev tile compute done; bow/s_cs ready at kt=0
#pragma unroll
        for (int pass = 0; pass < 8; ++pass) {
            int j = pass * 32 + jr;
            float4 w = pre[pass];
            int kl = q * 4;
            s_w1t[kl + 0][j] = w.x;
            s_w1t[kl + 1][j] = w.y;
            s_w1t[kl + 2][j] = w.z;
            s_w1t[kl + 3][j] = w.w;
        }
        __syncthreads();
        if (kt + 1 < HID / KT2) {
#pragma unroll
            for (int pass = 0; pass < 8; ++pass)
                pre[pass] = W1v[(size_t)(pass * 32 + jr) * 64 + (kt + 1) * 8 + q];
        }
#pragma unroll
        for (int ks = 0; ks < 8; ++ks) {
            const int kg = kt * KT2 + ks * 4;   // global k base
            const int kl = ks * 4;              // local k base
            float4 bb0 = *reinterpret_cast<const float4*>(&s_bow[rg * 4 + 0][kg]);
            float4 bb1 = *reinterpret_cast<const float4*>(&s_bow[rg * 4 + 1][kg]);
            float4 bb2 = *reinterpret_cast<const float4*>(&s_bow[rg * 4 + 2][kg]);
            float4 bb3 = *reinterpret_cast<const float4*>(&s_bow[rg * 4 + 3][kg]);
            float4 w0 = *reinterpret_cast<const float4*>(&s_w1t[kl + 0][cg * 4]);
            float4 w1 = *reinterpret_cast<const float4*>(&s_w1t[kl + 1][cg * 4]);
            float4 w2 = *reinterpret_cast<const float4*>(&s_w1t[kl + 2][cg * 4]);
            float4 w3 = *reinterpret_cast<const float4*>(&s_w1t[kl + 3][cg * 4]);
#define K2_ROW(r, bb)                                                          \
            acc[r][0] = fmaf(bb.x, w0.x, fmaf(bb.y, w1.x,                      \
                        fmaf(bb.z, w2.x, fmaf(bb.w, w3.x, acc[r][0]))));       \
            acc[r][1] = fmaf(bb.x, w0.y, fmaf(bb.y, w1.y,                      \
                        fmaf(bb.z, w2.y, fmaf(bb.w, w3.y, acc[r][1]))));       \
            acc[r][2] = fmaf(bb.x, w0.z, fmaf(bb.y, w1.z,                      \
                        fmaf(bb.z, w2.z, fmaf(bb.w, w3.z, acc[r][2]))));       \
            acc[r][3] = fmaf(bb.x, w0.w, fmaf(bb.y, w1.w,                      \
                        fmaf(bb.z, w2.w, fmaf(bb.w, w3.w, acc[r][3]))));
            K2_ROW(0, bb0)
            K2_ROW(1, bb1)
            K2_ROW(2, bb2)
            K2_ROW(3, bb3)
#undef K2_ROW
        }
    }

    // epilogue: write h (coalesced b128 per row), block-reduce BN partials
#pragma unroll
    for (int r = 0; r < 4; ++r) {
        float4 v;
        v.x = acc[r][0]; v.y = acc[r][1]; v.z = acc[r][2]; v.w = acc[r][3];
        *reinterpret_cast<float4*>(
            &hout[(size_t)(b0 + rg * 4 + r) * HID + cg * 4]) = v;
    }
#pragma unroll
    for (int c = 0; c < 4; ++c) {
        float ps  = ((acc[0][c] + acc[1][c]) + (acc[2][c] + acc[3][c]));
        float psq = ((acc[0][c] * acc[0][c] + acc[1][c] * acc[1][c])
                   + (acc[2][c] * acc[2][c] + acc[3][c] * acc[3][c]));
        atomicAdd(&s_cs[cg * 4 + c], ps);    // 4-way (rg) LDS atomic
        atomicAdd(&s_cq[cg * 4 + c], psq);
    }
    __syncthreads();
    atomicAdd(&colsum[tid], s_cs[tid]);
    atomicAdd(&colsq[tid], s_cq[tid]);
}

// ---------------------------------------------------------------------------
// k5: BN finalize (folded) + apply + ReLU + logits + BCE loss.
// 256 blocks; one wave per 4 rows; per-block LDS loss reduction.
// out[0] = loss, out[1..BATCH] = logits.
// ---------------------------------------------------------------------------
__global__ __launch_bounds__(256) void k5_bn_relu_logits_loss(
    const float* __restrict__ hmat,
    const float* __restrict__ colsum, const float* __restrict__ colsq,
    const float* __restrict__ gamma, const float* __restrict__ beta,
    const float* __restrict__ W2, const float* __restrict__ b2,
    const float* __restrict__ labels, float* __restrict__ out)
{
    __shared__ float s_loss[4];
    const int tid  = threadIdx.x;
    const int w    = tid >> 6;
    const int lane = tid & 63;
    const int b0   = blockIdx.x * 16 + w * 4;

    const int j0 = lane, j1 = lane + 64, j2 = lane + 128, j3 = lane + 192;

#define BN_SS(jj, sc, sh) \
    { float mu = colsum[jj] * (1.f / BATCH); \
      float vr = colsq[jj] * (1.f / BATCH) - mu * mu; \
      sc = gamma[jj] * rsqrtf(vr + BN_EPS); \
      sh = beta[jj] - mu * sc; }
    float sc0, sh0, sc1, sh1, sc2, sh2, sc3, sh3;
    BN_SS(j0, sc0, sh0); BN_SS(j1, sc1, sh1);
    BN_SS(j2, sc2, sh2); BN_SS(j3, sc3, sh3);
#undef BN_SS

    const float w0 = W2[j0], w1 = W2[j1], w2v = W2[j2], w3 = W2[j3];
    const float bias2 = b2[0];

    float bce_acc = 0.f;
#pragma unroll
    for (int rr = 0; rr < 4; ++rr) {
        const int b = b0 + rr;
        const float* hr = hmat + (size_t)b * HID;
        float h0 = hr[j0], h1 = hr[j1], h2 = hr[j2], h3 = hr[j3];
        float s = 0.f;
        s += fmaxf(fmaf(h0, sc0, sh0), 0.f) * w0;
        s += fmaxf(fmaf(h1, sc1, sh1), 0.f) * w1;
        s += fmaxf(fmaf(h2, sc2, sh2), 0.f) * w2v;
        s += fmaxf(fmaf(h3, sc3, sh3), 0.f) * w3;
#pragma unroll
        for (int off = 32; off > 0; off >>= 1)
            s += __shfl_down(s, off, 64);
        if (lane == 0) {
            float z = s + bias2;
            out[1 + b] = z;
            float lb = labels[b];
            bce_acc += fmaxf(z, 0.f) - z * lb + log1pf(expf(-fabsf(z)));
        }
    }
    if (lane == 0) s_loss[w] = bce_acc;
    __syncthreads();
    if (tid == 0) {
        float t = (s_loss[0] + s_loss[1]) + (s_loss[2] + s_loss[3]);
        atomicAdd(&out[0], t * (1.f / BATCH));
    }
}

// ---------------------------------------------------------------------------
extern "C" void kernel_launch(void* const* d_in, const int* in_sizes, int n_in,
                              void* d_out, int out_size, void* d_ws, size_t ws_size,
                              hipStream_t stream)
{
    const int*   token_ids   = (const int*)d_in[0];
    const int*   segment_ids = (const int*)d_in[1];
    const float* labels      = (const float*)d_in[2];
    const float* emb         = (const float*)d_in[3];
    const float* W1          = (const float*)d_in[4];
    const float* b1          = (const float*)d_in[5];
    const float* gamma       = (const float*)d_in[6];
    const float* beta        = (const float*)d_in[7];
    const float* W2          = (const float*)d_in[8];
    const float* b2          = (const float*)d_in[9];
    float* out = (float*)d_out;
    float* ws  = (float*)d_ws;

    float* seg_sum = ws + WS_SEGSUM;   // reused as h after k2
    float* counts  = ws + WS_COUNTS;
    float* colsum  = ws + WS_COLSUM;
    float* colsq   = ws + WS_COLSQ;

    const int T = in_sizes[0];
    const int g1 = (T + TPB1 - 1) / TPB1;

    if (ws_size >= WS_FP16_BYTES_NEEDED) {
        __half* emb16 = (__half*)((char*)d_ws + WS_EMB16_OFF_BYTES);
        const int n4  = VOCAB * HID / 4;
        const int nz4 = WS_ZERO_FLOATS / 4;
        k0_convert_zero<<<(n4 + 255) / 256, 256, 0, stream>>>(
            emb, emb16, (float4*)d_ws, n4, nz4);
        k1_gather_fp16<<<g1, 256, 0, stream>>>(token_ids, segment_ids, emb16,
                                               seg_sum, counts, T);
    } else {
        hipMemsetAsync(d_ws, 0, (size_t)WS_ZERO_FLOATS * sizeof(float), stream);
        k1_gather_fp32<<<g1, 256, 0, stream>>>(token_ids, segment_ids, emb,
                                               seg_sum, counts, T);
    }
    k2_gemm_bn<<<BATCH / 16, 256, 0, stream>>>(
        seg_sum, counts, W1, b1, /*hout=*/seg_sum, colsum, colsq, out);
    k5_bn_relu_logits_loss<<<BATCH / 16, 256, 0, stream>>>(
        seg_sum, colsum, colsq, gamma, beta, W2, b2, labels, out);
}